// Round 1
// baseline (395.089 us; speedup 1.0000x reference)
//
#include <hip/hip_runtime.h>
#include <cstdint>
#include <cstddef>

// SummaryAdapter fused kernel for MI355X (gfx950).
// L=8 B=2 S=4096 D=2048 N=128 Ds=1024 Da=64.
//
// Workspace layout (bytes):              size      end
//   bank_bf (B,N,Ds)  bf16        0    524288   524288
//   wk_bf   (L,Da,Ds) bf16   524288   1048576  1572864
//   wv_bf   (L,Da,Ds) bf16  1572864   1048576  2621440
//   KF  frag bf16           2621440    262144  2883584
//   VF  frag bf16           2883584    262144  3145728
//   WqF frag bf16           3145728   2097152  5242880
//   WoF frag bf16           5242880   2097152  7340032
// Requires ws_size >= 7340032.

typedef __attribute__((ext_vector_type(8))) short short8;   // 8 x bf16 (4 VGPR)
typedef __attribute__((ext_vector_type(4))) float f32x4;
typedef __attribute__((ext_vector_type(8))) unsigned short u16x8;
typedef __attribute__((ext_vector_type(4))) unsigned short u16x4;

#define MFMA16(a, b, c) __builtin_amdgcn_mfma_f32_16x16x32_bf16((a), (b), (c), 0, 0, 0)

__device__ __forceinline__ unsigned short f2bf(float f) {
  unsigned int x = __builtin_bit_cast(unsigned int, f);
  x += 0x7fffu + ((x >> 16) & 1u);        // RNE
  return (unsigned short)(x >> 16);
}
__device__ __forceinline__ float bf2f(unsigned short u) {
  return __builtin_bit_cast(float, (unsigned int)u << 16);
}
__device__ __forceinline__ short8 cvt8v(f32x4 a, f32x4 b) {
  short8 r;
  r[0] = (short)f2bf(a[0]); r[1] = (short)f2bf(a[1]);
  r[2] = (short)f2bf(a[2]); r[3] = (short)f2bf(a[3]);
  r[4] = (short)f2bf(b[0]); r[5] = (short)f2bf(b[1]);
  r[6] = (short)f2bf(b[2]); r[7] = (short)f2bf(b[3]);
  return r;
}

// ---------------- pre 1: f32 -> bf16 copies of bank, Wk, Wv ----------------
__global__ void pre_cvt_kernel(const float* __restrict__ bank, const float* __restrict__ Wk,
                               const float* __restrict__ Wv, unsigned short* __restrict__ bank_bf,
                               unsigned short* __restrict__ wk_bf, unsigned short* __restrict__ wv_bf) {
  int i = blockIdx.x * 256 + threadIdx.x;          // 524288 threads
  if (i < 262144) bank_bf[i] = f2bf(bank[i]);
  if (i < 524288) { wk_bf[i] = f2bf(Wk[i]); wv_bf[i] = f2bf(Wv[i]); }
}

// ---------------- pre 2: K = bank@Wk^T, V = bank@Wv^T via MFMA -------------
// grid 32: bid = ((l*2+b)*2 + kv). Writes KF/VF in B-fragment lane order.
__global__ __launch_bounds__(256)
void pre_kv_kernel(const unsigned short* __restrict__ bank_bf,
                   const unsigned short* __restrict__ wk_bf,
                   const unsigned short* __restrict__ wv_bf,
                   unsigned short* __restrict__ KF, unsigned short* __restrict__ VF) {
  int bid = blockIdx.x;
  int l = bid >> 2, b = (bid >> 1) & 1, kv = bid & 1;
  int tid = threadIdx.x, wave = tid >> 6, lane = tid & 63;
  int lo = lane & 15, hi = lane >> 4;
  const unsigned short* W  = (kv ? wv_bf : wk_bf) + l * 65536;
  const unsigned short* bk = bank_bf + b * 131072;
  int lbq = l * 2 + b;
  for (int it = 0; it < 2; ++it) {
    int nt = wave * 2 + it;                          // n-tile 0..7
    f32x4 acc[4];
    for (int at = 0; at < 4; ++at) acc[at] = (f32x4){0.f, 0.f, 0.f, 0.f};
    for (int ks = 0; ks < 32; ++ks) {
      short8 A = *(const short8*)(bk + (nt * 16 + lo) * 1024 + ks * 32 + hi * 8);
      #pragma unroll
      for (int at = 0; at < 4; ++at) {
        short8 B = *(const short8*)(W + (at * 16 + lo) * 1024 + ks * 32 + hi * 8);
        acc[at] = MFMA16(A, B, acc[at]);
      }
    }
    for (int at = 0; at < 4; ++at)
      for (int r = 0; r < 4; ++r) {
        int n = nt * 16 + hi * 4 + r;
        int a = at * 16 + lo;
        unsigned short v = f2bf(acc[at][r]);
        if (kv == 0) {  // KF[(lb,nt,ks)][lane][8]: n=nt*16+(ln&15), a=ks*32+(ln>>4)*8+j
          int idx = ((lbq * 8 + (n >> 4)) * 2 + (a >> 5)) * 512 +
                    (((a >> 3) & 3) * 16 + (n & 15)) * 8 + (a & 7);
          KF[idx] = v;
        } else {        // VF[(lb,at,ks)][lane][8]: a=at*16+(ln&15), n=ks*32+(ln>>4)*8+j
          int idx = ((lbq * 4 + (a >> 4)) * 4 + (n >> 5)) * 512 +
                    (((n >> 3) & 3) * 16 + (a & 15)) * 8 + (n & 7);
          VF[idx] = v;
        }
      }
  }
}

// ---------------- pre 3: Wq/Wo -> bf16 fragment layout ---------------------
__global__ void pre_frag_kernel(const float* __restrict__ Wq, const float* __restrict__ Wo,
                                unsigned short* __restrict__ WqF, unsigned short* __restrict__ WoF) {
  int idx = blockIdx.x * 256 + threadIdx.x;        // 262144 threads
  if (idx < 131072) {
    int t = idx;
    int lane = t & 63, ks = (t >> 6) & 63, at = (t >> 12) & 3, l = t >> 14;
    int a = at * 16 + (lane & 15), d = ks * 32 + (lane >> 4) * 8;
    const float* src = Wq + ((size_t)(l * 64 + a)) * 2048 + d;
    f32x4 v0 = *(const f32x4*)src, v1 = *(const f32x4*)(src + 4);
    *(short8*)(WqF + (size_t)t * 8) = cvt8v(v0, v1);
  } else {
    int t = idx - 131072;
    int lane = t & 63, ks = (t >> 6) & 1, dt = (t >> 7) & 127, l = t >> 14;
    int d = dt * 16 + (lane & 15), a = ks * 32 + (lane >> 4) * 8;
    const float* src = Wo + ((size_t)(l * 2048 + d)) * 64 + a;
    f32x4 v0 = *(const f32x4*)src, v1 = *(const f32x4*)(src + 4);
    *(short8*)(WoF + (size_t)t * 8) = cvt8v(v0, v1);
  }
}

// ---------------- main fused kernel ----------------------------------------
// grid 2048 = (l:8, b:2, stile:128), 512 threads (8 waves), 156672 B dynamic LDS.
//   h_lds : bf16 [32][2048], swizzled byte ^= (row&7)<<4, 131072 B
//   qa    : f32 [32][68] (Q, then P bf16 [32][136], then attn_out) 8704 B
//   s_lds : f32 [32][132]                                          16896 B
__global__ __launch_bounds__(512, 1)
void adapter_main(const float* __restrict__ hidden,
                  const unsigned short* __restrict__ KF, const unsigned short* __restrict__ VF,
                  const unsigned short* __restrict__ WqF, const unsigned short* __restrict__ WoF,
                  const float* __restrict__ gates, float* __restrict__ out) {
  extern __shared__ char smem[];
  float* qa = (float*)(smem + 131072);
  float* s_lds = (float*)(smem + 131072 + 8704);

  int bid = blockIdx.x;
  int st = bid & 127, b = (bid >> 7) & 1, l = bid >> 8;
  int s0 = st * 32;
  int tid = threadIdx.x, wave = tid >> 6, lane = tid & 63;
  int lo = lane & 15, hi = lane >> 4;
  size_t hbase = ((size_t)(l * 2 + b) * 4096 + s0) * 2048;
  const float* hsrc = hidden + hbase;

  // ---- Phase 0: stage hidden tile -> LDS bf16 (swizzled) ----
  #pragma unroll
  for (int it = 0; it < 16; ++it) {
    int chunk = tid + it * 512;                 // 8192 chunks of 8 f32
    int row = chunk >> 8, c = chunk & 255;
    const float* src = hsrc + row * 2048 + c * 8;
    f32x4 v0 = *(const f32x4*)src, v1 = *(const f32x4*)(src + 4);
    int byte = row * 4096 + ((c * 16) ^ ((row & 7) << 4));
    *(short8*)(smem + byte) = cvt8v(v0, v1);
  }
  __syncthreads();

  int mt = wave >> 2;                            // 0..1 : 16-row half
  int at = wave & 3;                             // 0..3 : Da 16-col tile

  // ---- Phase 1: Q = h @ Wq^T (per wave one 16x16 C-tile, K=2048) ----
  {
    f32x4 acc = {0.f, 0.f, 0.f, 0.f};
    int arow = mt * 16 + lo;
    int abase = arow * 4096, sw = (arow & 7) << 4;
    const unsigned short* wq = WqF + ((size_t)(l * 4 + at) * 64) * 512 + lane * 8;
    #pragma unroll 8
    for (int ks = 0; ks < 64; ++ks) {
      short8 A = *(const short8*)(smem + abase + ((ks * 64 + hi * 16) ^ sw));
      short8 B = *(const short8*)(wq + ks * 512);
      acc = MFMA16(A, B, acc);
    }
    #pragma unroll
    for (int r = 0; r < 4; ++r)                  // fold 1/sqrt(64) into Q
      qa[(mt * 16 + hi * 4 + r) * 68 + at * 16 + lo] = acc[r] * 0.125f;
  }
  __syncthreads();

  // ---- Phase 2: scores = Q @ K^T -> s_lds ----
  {
    short8 afrag[2];
    #pragma unroll
    for (int ks = 0; ks < 2; ++ks) {
      const float* qp = qa + (mt * 16 + lo) * 68 + ks * 32 + hi * 8;
      afrag[ks] = cvt8v(*(const f32x4*)qp, *(const f32x4*)(qp + 4));
    }
    #pragma unroll
    for (int i = 0; i < 2; ++i) {
      int nt = (wave & 3) * 2 + i;               // 0..7
      f32x4 acc = {0.f, 0.f, 0.f, 0.f};
      const unsigned short* kf = KF + ((size_t)((l * 2 + b) * 8 + nt) * 2) * 512 + lane * 8;
      acc = MFMA16(afrag[0], *(const short8*)(kf), acc);
      acc = MFMA16(afrag[1], *(const short8*)(kf + 512), acc);
      #pragma unroll
      for (int r = 0; r < 4; ++r)
        s_lds[(mt * 16 + hi * 4 + r) * 132 + nt * 16 + lo] = acc[r];
    }
  }
  __syncthreads();

  // ---- Phase 3: softmax over N=128 (16 lanes per row), write P bf16 into qa region ----
  {
    int row = wave * 4 + hi;
    const float* sp = s_lds + row * 132 + lo * 8;
    f32x4 v0 = *(const f32x4*)sp, v1 = *(const f32x4*)(sp + 4);
    float m = fmaxf(fmaxf(fmaxf(v0[0], v0[1]), fmaxf(v0[2], v0[3])),
                    fmaxf(fmaxf(v1[0], v1[1]), fmaxf(v1[2], v1[3])));
    m = fmaxf(m, __shfl_xor(m, 1)); m = fmaxf(m, __shfl_xor(m, 2));
    m = fmaxf(m, __shfl_xor(m, 4)); m = fmaxf(m, __shfl_xor(m, 8));
    f32x4 e0, e1; float s = 0.f;
    #pragma unroll
    for (int j = 0; j < 4; ++j) { e0[j] = __expf(v0[j] - m); s += e0[j]; }
    #pragma unroll
    for (int j = 0; j < 4; ++j) { e1[j] = __expf(v1[j] - m); s += e1[j]; }
    s += __shfl_xor(s, 1); s += __shfl_xor(s, 2);
    s += __shfl_xor(s, 4); s += __shfl_xor(s, 8);
    float inv = 1.0f / s;
    #pragma unroll
    for (int j = 0; j < 4; ++j) { e0[j] *= inv; e1[j] *= inv; }
    *(short8*)(smem + 131072 + row * 272 + lo * 16) = cvt8v(e0, e1);
  }
  __syncthreads();

  // ---- Phase 4: attn_out = P @ V ----
  f32x4 aoacc = {0.f, 0.f, 0.f, 0.f};
  {
    const unsigned short* vf = VF + ((size_t)((l * 2 + b) * 4 + at) * 4) * 512 + lane * 8;
    int prow = mt * 16 + lo;
    #pragma unroll
    for (int ks = 0; ks < 4; ++ks) {
      short8 A = *(const short8*)(smem + 131072 + prow * 272 + ks * 64 + hi * 16);
      short8 B = *(const short8*)(vf + ks * 512);
      aoacc = MFMA16(A, B, aoacc);
    }
  }
  __syncthreads();                               // all P reads done
  #pragma unroll
  for (int r = 0; r < 4; ++r)
    qa[(mt * 16 + hi * 4 + r) * 68 + at * 16 + lo] = aoacc[r];
  __syncthreads();

  // ---- Phase 5: resid^T = Wo @ attn_out^T, epilogue out = h + g*resid ----
  {
    float gate = 1.0f / (1.0f + __expf(-gates[l]));
    short8 bfrag[2][2];                          // attn_out^T B-fragments
    #pragma unroll
    for (int m2 = 0; m2 < 2; ++m2)
      #pragma unroll
      for (int ks = 0; ks < 2; ++ks) {
        const float* ap = qa + (m2 * 16 + lo) * 68 + ks * 32 + hi * 8;
        bfrag[m2][ks] = cvt8v(*(const f32x4*)ap, *(const f32x4*)(ap + 4));
      }
    #pragma unroll 4
    for (int i = 0; i < 16; ++i) {
      int dt = wave + i * 8;                     // 0..127 d-tile
      const unsigned short* wo = WoF + ((size_t)(l * 128 + dt) * 2) * 512 + lane * 8;
      short8 A0 = *(const short8*)(wo);
      short8 A1 = *(const short8*)(wo + 512);
      #pragma unroll
      for (int m2 = 0; m2 < 2; ++m2) {
        f32x4 acc = {0.f, 0.f, 0.f, 0.f};
        acc = MFMA16(A0, bfrag[m2][0], acc);
        acc = MFMA16(A1, bfrag[m2][1], acc);
        int srow = m2 * 16 + lo;                 // s within tile (D-layout col)
        int d0 = dt * 16 + hi * 4;               // 4 consecutive d (D-layout rows)
        u16x4 hv = *(const u16x4*)(smem + srow * 4096 + ((d0 * 2) ^ ((srow & 7) << 4)));
        f32x4 o;
        #pragma unroll
        for (int r = 0; r < 4; ++r) o[r] = bf2f(hv[r]) + gate * acc[r];
        *(f32x4*)(out + hbase + (size_t)srow * 2048 + d0) = o;
      }
    }
  }
}

extern "C" void kernel_launch(void* const* d_in, const int* in_sizes, int n_in,
                              void* d_out, int out_size, void* d_ws, size_t ws_size,
                              hipStream_t stream) {
  const float* hidden = (const float*)d_in[0];
  const float* bank   = (const float*)d_in[1];
  const float* Wq     = (const float*)d_in[2];
  const float* Wk     = (const float*)d_in[3];
  const float* Wv     = (const float*)d_in[4];
  const float* Wo     = (const float*)d_in[5];
  const float* gates  = (const float*)d_in[6];
  float* out = (float*)d_out;

  char* ws = (char*)d_ws;
  unsigned short* bank_bf = (unsigned short*)(ws);
  unsigned short* wk_bf   = (unsigned short*)(ws + 524288);
  unsigned short* wv_bf   = (unsigned short*)(ws + 1572864);
  unsigned short* KF      = (unsigned short*)(ws + 2621440);
  unsigned short* VF      = (unsigned short*)(ws + 2883584);
  unsigned short* WqF     = (unsigned short*)(ws + 3145728);
  unsigned short* WoF     = (unsigned short*)(ws + 5242880);

  pre_cvt_kernel<<<2048, 256, 0, stream>>>(bank, Wk, Wv, bank_bf, wk_bf, wv_bf);
  pre_kv_kernel<<<32, 256, 0, stream>>>(bank_bf, wk_bf, wv_bf, KF, VF);
  pre_frag_kernel<<<1024, 256, 0, stream>>>(Wq, Wo, WqF, WoF);

  (void)hipFuncSetAttribute(reinterpret_cast<const void*>(adapter_main),
                            hipFuncAttributeMaxDynamicSharedMemorySize, 156672);
  adapter_main<<<2048, 512, 156672, stream>>>(hidden, KF, VF, WqF, WoF, gates, out);
}